// Round 1
// baseline (4236.496 us; speedup 1.0000x reference)
//
#include <hip/hip_runtime.h>

#define N_NODES 100000
#define N_EDGES 1600000
#define IN_C    64
#define HID_C   128
#define OUT_C   64
#define N_CLS   20

// ---------------------------------------------------------------------------
// Workspace layout (floats):
//   [0,      N)        deg  -> deg_inv (inverted in place)
//   [N,      65N)      agg1 (N x 64)   ; reused as h2 (N x 64) after dense1
//   [65N,    193N)     h1   (N x 128)
//   [193N,   321N)     agg2 (N x 128)
// total = 321N floats = 128.4 MB
// ---------------------------------------------------------------------------

// Edge-parallel scatter for layer 1: 16 threads/edge, each does a float4 gather
// from x[src] and 4 scalar float atomics into agg1[dst]. q==0 also bumps deg.
__global__ __launch_bounds__(256) void scatter1_kernel(
        const int* __restrict__ ei, const float* __restrict__ x,
        float* __restrict__ agg, float* __restrict__ deg)
{
    int gid = blockIdx.x * 256 + threadIdx.x;
    int e = gid >> 4;
    int q = gid & 15;
    if (e >= N_EDGES) return;
    int src = ei[e];
    int dst = ei[N_EDGES + e];
    float4 v = ((const float4*)x)[(size_t)src * 16 + q];
    float* a = agg + (size_t)dst * 64 + q * 4;
    atomicAdd(a + 0, v.x);
    atomicAdd(a + 1, v.y);
    atomicAdd(a + 2, v.z);
    atomicAdd(a + 3, v.w);
    if (q == 0) atomicAdd(deg + dst, 1.0f);
}

// Edge-parallel scatter for layer 2: 32 threads/edge (128 channels).
__global__ __launch_bounds__(256) void scatter2_kernel(
        const int* __restrict__ ei, const float* __restrict__ h,
        float* __restrict__ agg)
{
    int gid = blockIdx.x * 256 + threadIdx.x;
    int e = gid >> 5;
    int q = gid & 31;
    if (e >= N_EDGES) return;
    int src = ei[e];
    int dst = ei[N_EDGES + e];
    float4 v = ((const float4*)h)[(size_t)src * 32 + q];
    float* a = agg + (size_t)dst * 128 + q * 4;
    atomicAdd(a + 0, v.x);
    atomicAdd(a + 1, v.y);
    atomicAdd(a + 2, v.z);
    atomicAdd(a + 3, v.w);
}

__global__ __launch_bounds__(256) void deg_inv_kernel(float* __restrict__ deg)
{
    int i = blockIdx.x * 256 + threadIdx.x;
    if (i < N_NODES) {
        float d = deg[i];
        deg[i] = 1.0f / fmaxf(d, 1.0f);
    }
}

// Fused SAGE dense layer: out = act( self@Wself + (agg*deg_inv)@Wneigh + b )
// Tiled: 64 nodes/block, z = [self | neigh*dinv] staged in LDS in 64-k chunks.
// Threads: 256. Each thread owns TM nodes x 4 output cols (float4 acc).
template<int IN, int OUT, bool RELU>
__global__ __launch_bounds__(256) void dense_kernel(
        const float* __restrict__ sf,    // [N, IN] self features
        const float* __restrict__ ag,    // [N, IN] neighbor sums
        const float* __restrict__ dinv,  // [N]
        const float* __restrict__ wsp,   // [IN, OUT]
        const float* __restrict__ wnp,   // [IN, OUT]
        const float* __restrict__ bias,  // [OUT]
        float* __restrict__ out,         // [N, OUT]
        int n_nodes)
{
    constexpr int BM = 64;
    constexpr int C4 = OUT / 4;            // 32 (L1) or 16 (L2)
    constexpr int NG = 256 / C4;           // 8 or 16 node groups
    constexpr int TM = BM / NG;            // 8 or 4 nodes per thread
    constexpr int KC = 64;                 // k-chunk staged in LDS
    constexpr int SELF_CHUNKS = IN / KC;   // 1 or 2
    constexpr int NCHUNK = 2 * SELF_CHUNKS;
    constexpr int LSTRIDE = KC + 4;        // pad, keeps float4 row alignment

    __shared__ float zs[BM * LSTRIDE];

    const int tid = threadIdx.x;
    const int node0 = blockIdx.x * BM;
    const int c = tid % C4;                // col group: cols [4c, 4c+4)
    const int g = tid / C4;                // node group: nodes [g*TM, g*TM+TM)

    float acc[TM][4];
#pragma unroll
    for (int i = 0; i < TM; ++i) {
        acc[i][0] = 0.f; acc[i][1] = 0.f; acc[i][2] = 0.f; acc[i][3] = 0.f;
    }

    for (int ch = 0; ch < NCHUNK; ++ch) {
        const bool is_neigh = (ch >= SELF_CHUNKS);
        const int kbase = (ch % SELF_CHUNKS) * KC;
        const float* __restrict__ srcp = is_neigh ? ag : sf;

        __syncthreads();  // protect zs from previous chunk's readers
        // stage: BM nodes x KC floats = 1024 float4 over 256 threads
        for (int t = tid; t < BM * (KC / 4); t += 256) {
            int n  = t / (KC / 4);
            int k4 = t % (KC / 4);
            int node = node0 + n;
            float4 v = make_float4(0.f, 0.f, 0.f, 0.f);
            if (node < n_nodes) {
                v = *(const float4*)(srcp + (size_t)node * IN + kbase + k4 * 4);
                if (is_neigh) {
                    float di = dinv[node];
                    v.x *= di; v.y *= di; v.z *= di; v.w *= di;
                }
            }
            float* d = zs + n * LSTRIDE + k4 * 4;
            d[0] = v.x; d[1] = v.y; d[2] = v.z; d[3] = v.w;
        }
        __syncthreads();

        const float* __restrict__ wrow =
            (is_neigh ? wnp : wsp) + (size_t)kbase * OUT + c * 4;
        for (int k = 0; k < KC; ++k) {
            float4 w = *(const float4*)(wrow + (size_t)k * OUT);
#pragma unroll
            for (int i = 0; i < TM; ++i) {
                float z = zs[(g * TM + i) * LSTRIDE + k];
                acc[i][0] += z * w.x;
                acc[i][1] += z * w.y;
                acc[i][2] += z * w.z;
                acc[i][3] += z * w.w;
            }
        }
    }

    float4 bv = *(const float4*)(bias + c * 4);
#pragma unroll
    for (int i = 0; i < TM; ++i) {
        int node = node0 + g * TM + i;
        if (node >= n_nodes) continue;
        float4 r;
        r.x = acc[i][0] + bv.x;
        r.y = acc[i][1] + bv.y;
        r.z = acc[i][2] + bv.z;
        r.w = acc[i][3] + bv.w;
        if (RELU) {
            r.x = fmaxf(r.x, 0.f); r.y = fmaxf(r.y, 0.f);
            r.z = fmaxf(r.z, 0.f); r.w = fmaxf(r.w, 0.f);
        }
        *(float4*)(out + (size_t)node * OUT + c * 4) = r;
    }
}

// out[n, cls] = h2[n, :] @ wc[:, cls] + bc[cls]
__global__ __launch_bounds__(256) void classifier_kernel(
        const float* __restrict__ h,   // [N, 64]
        const float* __restrict__ wc,  // [64, 20]
        const float* __restrict__ bc,  // [20]
        float* __restrict__ out, int n_nodes)
{
    constexpr int NB = 32;
    __shared__ float hs[NB][68];
    __shared__ float wcs[64 * N_CLS];
    __shared__ float bcs[N_CLS];

    const int tid = threadIdx.x;
    const int node0 = blockIdx.x * NB;

    for (int t = tid; t < 64 * N_CLS; t += 256) wcs[t] = wc[t];
    if (tid < N_CLS) bcs[tid] = bc[tid];

    for (int t = tid; t < NB * 16; t += 256) {
        int n = t / 16, k4 = t % 16;
        float4 v = make_float4(0.f, 0.f, 0.f, 0.f);
        if (node0 + n < n_nodes)
            v = ((const float4*)(h + (size_t)(node0 + n) * 64))[k4];
        hs[n][k4 * 4 + 0] = v.x; hs[n][k4 * 4 + 1] = v.y;
        hs[n][k4 * 4 + 2] = v.z; hs[n][k4 * 4 + 3] = v.w;
    }
    __syncthreads();

    for (int o = tid; o < NB * N_CLS; o += 256) {
        int n = o / N_CLS, cls = o % N_CLS;
        if (node0 + n >= n_nodes) continue;
        float s = bcs[cls];
#pragma unroll
        for (int k = 0; k < 64; ++k) s += hs[n][k] * wcs[k * N_CLS + cls];
        out[(size_t)(node0 + n) * N_CLS + cls] = s;
    }
}

extern "C" void kernel_launch(void* const* d_in, const int* in_sizes, int n_in,
                              void* d_out, int out_size, void* d_ws, size_t ws_size,
                              hipStream_t stream)
{
    const float* x        = (const float*)d_in[0];
    const int*   ei       = (const int*)  d_in[1];
    const float* w_self1  = (const float*)d_in[2];
    const float* w_neigh1 = (const float*)d_in[3];
    const float* b1       = (const float*)d_in[4];
    const float* w_self2  = (const float*)d_in[5];
    const float* w_neigh2 = (const float*)d_in[6];
    const float* b2       = (const float*)d_in[7];
    const float* wc       = (const float*)d_in[8];
    const float* bc       = (const float*)d_in[9];
    float* out = (float*)d_out;
    float* ws  = (float*)d_ws;

    const size_t N = N_NODES;
    float* deg  = ws;             // N floats (becomes deg_inv)
    float* agg1 = ws + N;         // N x 64
    float* h1   = ws + 65 * N;    // N x 128
    float* agg2 = ws + 193 * N;   // N x 128
    float* h2   = agg1;           // agg1 dead after dense1 -> reuse for h2

    // zero deg + agg1 (contiguous) and agg2; ws is re-poisoned before each call
    hipMemsetAsync(deg,  0, 65 * N * sizeof(float), stream);
    hipMemsetAsync(agg2, 0, 128 * N * sizeof(float), stream);

    scatter1_kernel<<<(N_EDGES * 16) / 256, 256, 0, stream>>>(ei, x, agg1, deg);
    deg_inv_kernel<<<(N_NODES + 255) / 256, 256, 0, stream>>>(deg);
    dense_kernel<IN_C, HID_C, true><<<(N_NODES + 63) / 64, 256, 0, stream>>>(
        x, agg1, deg, w_self1, w_neigh1, b1, h1, N_NODES);
    scatter2_kernel<<<(N_EDGES * 32) / 256, 256, 0, stream>>>(ei, h1, agg2);
    dense_kernel<HID_C, OUT_C, true><<<(N_NODES + 63) / 64, 256, 0, stream>>>(
        h1, agg2, deg, w_self2, w_neigh2, b2, h2, N_NODES);
    classifier_kernel<<<(N_NODES + 31) / 32, 256, 0, stream>>>(h2, wc, bc, out, N_NODES);
}

// Round 2
// 594.329 us; speedup vs baseline: 7.1282x; 7.1282x over previous
//
#include <hip/hip_runtime.h>

#define N_NODES 100000
#define N_EDGES 1600000
#define IN_C    64
#define HID_C   128
#define OUT_C   64
#define N_CLS   20

// ---------------------------------------------------------------------------
// CSR-based SAGE. Workspace layout:
//   ints:   deg_i[N] | row_ptr[N+4] | cursor[N] | bsum[128] | sorted_src[E]
//   floats: dinv[N] | agg1[64N] | h1[128N] | agg2[128N]     (h2 reuses agg1)
// total ~136 MB. All float4 regions 16B-aligned by construction.
// ---------------------------------------------------------------------------

// ---- CSR build ------------------------------------------------------------

__global__ __launch_bounds__(256) void count_kernel(
        const int* __restrict__ ei, int* __restrict__ deg)
{
    int e = blockIdx.x * 256 + threadIdx.x;
    if (e >= N_EDGES) return;
    atomicAdd(&deg[ei[N_EDGES + e]], 1);
}

// per-1024-element block scan: writes exclusive partial into part, block total
// into bsum.
__global__ __launch_bounds__(256) void scan1_kernel(
        const int* __restrict__ deg, int* __restrict__ part,
        int* __restrict__ bsum, int n)
{
    __shared__ int sd[256];
    int tid = threadIdx.x;
    int base = blockIdx.x * 1024 + tid * 4;
    int v0 = 0, v1 = 0, v2 = 0, v3 = 0;
    if (base + 0 < n) v0 = deg[base + 0];
    if (base + 1 < n) v1 = deg[base + 1];
    if (base + 2 < n) v2 = deg[base + 2];
    if (base + 3 < n) v3 = deg[base + 3];
    int i0 = v0, i1 = v0 + v1, i2 = i1 + v2, i3 = i2 + v3;
    sd[tid] = i3;
    __syncthreads();
    for (int off = 1; off < 256; off <<= 1) {
        int x = 0;
        if (tid >= off) x = sd[tid - off];
        __syncthreads();
        if (tid >= off) sd[tid] += x;
        __syncthreads();
    }
    int excl = sd[tid] - i3;
    if (base + 0 < n) part[base + 0] = excl;
    if (base + 1 < n) part[base + 1] = excl + i0;
    if (base + 2 < n) part[base + 2] = excl + i1;
    if (base + 3 < n) part[base + 3] = excl + i2;
    if (tid == 255) bsum[blockIdx.x] = sd[255];
}

// single-block exclusive scan of <=256 block sums
__global__ __launch_bounds__(256) void scan2_kernel(int* __restrict__ bsum, int nb)
{
    __shared__ int sd[256];
    int tid = threadIdx.x;
    int v = (tid < nb) ? bsum[tid] : 0;
    sd[tid] = v;
    __syncthreads();
    for (int off = 1; off < 256; off <<= 1) {
        int x = 0;
        if (tid >= off) x = sd[tid - off];
        __syncthreads();
        if (tid >= off) sd[tid] += x;
        __syncthreads();
    }
    if (tid < nb) bsum[tid] = sd[tid] - v;
}

__global__ __launch_bounds__(256) void scan3_kernel(
        int* __restrict__ row_ptr, const int* __restrict__ bsum, int n)
{
    int i = blockIdx.x * 256 + threadIdx.x;
    if (i < n) row_ptr[i] += bsum[i >> 10];
    if (i == n) row_ptr[n] = N_EDGES;
}

__global__ __launch_bounds__(256) void fill_kernel(
        const int* __restrict__ ei, const int* __restrict__ row_ptr,
        int* __restrict__ cursor, int* __restrict__ sorted_src)
{
    int e = blockIdx.x * 256 + threadIdx.x;
    if (e >= N_EDGES) return;
    int src = ei[e];
    int dst = ei[N_EDGES + e];
    int pos = atomicAdd(&cursor[dst], 1);
    sorted_src[row_ptr[dst] + pos] = src;
}

__global__ __launch_bounds__(256) void dinv_kernel(
        const int* __restrict__ deg, float* __restrict__ dinv)
{
    int i = blockIdx.x * 256 + threadIdx.x;
    if (i < N_NODES) dinv[i] = 1.0f / (float)max(deg[i], 1);
}

// ---- gather-aggregate (mean fused) ----------------------------------------
// C channels, T=C/4 threads per node, each owns a float4 chunk.
template<int C>
__global__ __launch_bounds__(256) void gather_kernel(
        const int* __restrict__ row_ptr, const int* __restrict__ srcs,
        const float* __restrict__ feat, const float* __restrict__ dinv,
        float* __restrict__ agg)
{
    constexpr int T = C / 4;
    int gid = blockIdx.x * 256 + threadIdx.x;
    int n = gid / T;
    int q = gid % T;
    if (n >= N_NODES) return;
    int beg = row_ptr[n];
    int end = row_ptr[n + 1];
    const float4* f4 = (const float4*)feat;
    float4 acc = make_float4(0.f, 0.f, 0.f, 0.f);
    for (int e = beg; e < end; ++e) {
        int s = srcs[e];
        float4 v = f4[(size_t)s * T + q];
        acc.x += v.x; acc.y += v.y; acc.z += v.z; acc.w += v.w;
    }
    float di = dinv[n];
    acc.x *= di; acc.y *= di; acc.z *= di; acc.w *= di;
    ((float4*)agg)[(size_t)n * T + q] = acc;
}

// ---- dense layers ---------------------------------------------------------
// out = act( self@Wself + agg@Wneigh + b ); agg is already mean-normalized.
template<int IN, int OUT, bool RELU>
__global__ __launch_bounds__(256) void dense_kernel(
        const float* __restrict__ sf,    // [N, IN]
        const float* __restrict__ ag,    // [N, IN]
        const float* __restrict__ wsp,   // [IN, OUT]
        const float* __restrict__ wnp,   // [IN, OUT]
        const float* __restrict__ bias,  // [OUT]
        float* __restrict__ out,         // [N, OUT]
        int n_nodes)
{
    constexpr int BM = 64;
    constexpr int C4 = OUT / 4;
    constexpr int NG = 256 / C4;
    constexpr int TM = BM / NG;
    constexpr int KC = 64;
    constexpr int SELF_CHUNKS = IN / KC;
    constexpr int NCHUNK = 2 * SELF_CHUNKS;
    constexpr int LSTRIDE = KC + 4;

    __shared__ float zs[BM * LSTRIDE];

    const int tid = threadIdx.x;
    const int node0 = blockIdx.x * BM;
    const int c = tid % C4;
    const int g = tid / C4;

    float acc[TM][4];
#pragma unroll
    for (int i = 0; i < TM; ++i) {
        acc[i][0] = 0.f; acc[i][1] = 0.f; acc[i][2] = 0.f; acc[i][3] = 0.f;
    }

    for (int ch = 0; ch < NCHUNK; ++ch) {
        const bool is_neigh = (ch >= SELF_CHUNKS);
        const int kbase = (ch % SELF_CHUNKS) * KC;
        const float* __restrict__ srcp = is_neigh ? ag : sf;

        __syncthreads();
        for (int t = tid; t < BM * (KC / 4); t += 256) {
            int n  = t / (KC / 4);
            int k4 = t % (KC / 4);
            int node = node0 + n;
            float4 v = make_float4(0.f, 0.f, 0.f, 0.f);
            if (node < n_nodes)
                v = *(const float4*)(srcp + (size_t)node * IN + kbase + k4 * 4);
            float* d = zs + n * LSTRIDE + k4 * 4;
            d[0] = v.x; d[1] = v.y; d[2] = v.z; d[3] = v.w;
        }
        __syncthreads();

        const float* __restrict__ wrow =
            (is_neigh ? wnp : wsp) + (size_t)kbase * OUT + c * 4;
        for (int k = 0; k < KC; ++k) {
            float4 w = *(const float4*)(wrow + (size_t)k * OUT);
#pragma unroll
            for (int i = 0; i < TM; ++i) {
                float z = zs[(g * TM + i) * LSTRIDE + k];
                acc[i][0] += z * w.x;
                acc[i][1] += z * w.y;
                acc[i][2] += z * w.z;
                acc[i][3] += z * w.w;
            }
        }
    }

    float4 bv = *(const float4*)(bias + c * 4);
#pragma unroll
    for (int i = 0; i < TM; ++i) {
        int node = node0 + g * TM + i;
        if (node >= n_nodes) continue;
        float4 r;
        r.x = acc[i][0] + bv.x;
        r.y = acc[i][1] + bv.y;
        r.z = acc[i][2] + bv.z;
        r.w = acc[i][3] + bv.w;
        if (RELU) {
            r.x = fmaxf(r.x, 0.f); r.y = fmaxf(r.y, 0.f);
            r.z = fmaxf(r.z, 0.f); r.w = fmaxf(r.w, 0.f);
        }
        *(float4*)(out + (size_t)node * OUT + c * 4) = r;
    }
}

__global__ __launch_bounds__(256) void classifier_kernel(
        const float* __restrict__ h, const float* __restrict__ wc,
        const float* __restrict__ bc, float* __restrict__ out, int n_nodes)
{
    constexpr int NB = 32;
    __shared__ float hs[NB][68];
    __shared__ float wcs[64 * N_CLS];
    __shared__ float bcs[N_CLS];

    const int tid = threadIdx.x;
    const int node0 = blockIdx.x * NB;

    for (int t = tid; t < 64 * N_CLS; t += 256) wcs[t] = wc[t];
    if (tid < N_CLS) bcs[tid] = bc[tid];

    for (int t = tid; t < NB * 16; t += 256) {
        int n = t / 16, k4 = t % 16;
        float4 v = make_float4(0.f, 0.f, 0.f, 0.f);
        if (node0 + n < n_nodes)
            v = ((const float4*)(h + (size_t)(node0 + n) * 64))[k4];
        hs[n][k4 * 4 + 0] = v.x; hs[n][k4 * 4 + 1] = v.y;
        hs[n][k4 * 4 + 2] = v.z; hs[n][k4 * 4 + 3] = v.w;
    }
    __syncthreads();

    for (int o = tid; o < NB * N_CLS; o += 256) {
        int n = o / N_CLS, cls = o % N_CLS;
        if (node0 + n >= n_nodes) continue;
        float s = bcs[cls];
#pragma unroll
        for (int k = 0; k < 64; ++k) s += hs[n][k] * wcs[k * N_CLS + cls];
        out[(size_t)(node0 + n) * N_CLS + cls] = s;
    }
}

extern "C" void kernel_launch(void* const* d_in, const int* in_sizes, int n_in,
                              void* d_out, int out_size, void* d_ws, size_t ws_size,
                              hipStream_t stream)
{
    const float* x        = (const float*)d_in[0];
    const int*   ei       = (const int*)  d_in[1];
    const float* w_self1  = (const float*)d_in[2];
    const float* w_neigh1 = (const float*)d_in[3];
    const float* b1       = (const float*)d_in[4];
    const float* w_self2  = (const float*)d_in[5];
    const float* w_neigh2 = (const float*)d_in[6];
    const float* b2       = (const float*)d_in[7];
    const float* wc       = (const float*)d_in[8];
    const float* bc       = (const float*)d_in[9];
    float* out = (float*)d_out;

    const size_t N = N_NODES;
    int*   deg_i      = (int*)d_ws;
    int*   row_ptr    = deg_i + N;          // N+4 slots (padded for alignment)
    int*   cursor     = row_ptr + N + 4;
    int*   bsum       = cursor + N;         // 128 slots
    int*   sorted_src = bsum + 128;
    float* dinv       = (float*)(sorted_src + N_EDGES);
    float* agg1       = dinv + N;           // N x 64
    float* h1         = agg1 + 64 * N;      // N x 128
    float* agg2       = h1 + 128 * N;       // N x 128
    float* h2         = agg1;               // reuse after dense1

    hipMemsetAsync(deg_i,  0, N * sizeof(int), stream);
    hipMemsetAsync(cursor, 0, N * sizeof(int), stream);

    const int EB = (N_EDGES + 255) / 256;
    const int NB1024 = (N_NODES + 1023) / 1024;

    count_kernel<<<EB, 256, 0, stream>>>(ei, deg_i);
    scan1_kernel<<<NB1024, 256, 0, stream>>>(deg_i, row_ptr, bsum, N_NODES);
    scan2_kernel<<<1, 256, 0, stream>>>(bsum, NB1024);
    scan3_kernel<<<(N_NODES + 256) / 256, 256, 0, stream>>>(row_ptr, bsum, N_NODES);
    fill_kernel<<<EB, 256, 0, stream>>>(ei, row_ptr, cursor, sorted_src);
    dinv_kernel<<<(N_NODES + 255) / 256, 256, 0, stream>>>(deg_i, dinv);

    gather_kernel<IN_C><<<(N_NODES * 16 + 255) / 256, 256, 0, stream>>>(
        row_ptr, sorted_src, x, dinv, agg1);
    dense_kernel<IN_C, HID_C, true><<<(N_NODES + 63) / 64, 256, 0, stream>>>(
        x, agg1, w_self1, w_neigh1, b1, h1, N_NODES);
    gather_kernel<HID_C><<<(N_NODES * 32 + 255) / 256, 256, 0, stream>>>(
        row_ptr, sorted_src, h1, dinv, agg2);
    dense_kernel<HID_C, OUT_C, true><<<(N_NODES + 63) / 64, 256, 0, stream>>>(
        h1, agg2, w_self2, w_neigh2, b2, h2, N_NODES);
    classifier_kernel<<<(N_NODES + 31) / 32, 256, 0, stream>>>(h2, wc, bc, out, N_NODES);
}

// Round 3
// 467.744 us; speedup vs baseline: 9.0573x; 1.2706x over previous
//
#include <hip/hip_runtime.h>

#define N_NODES 100000
#define N_EDGES 1600000
#define IN_C    64
#define HID_C   128
#define OUT_C   64
#define N_CLS   20

typedef __attribute__((ext_vector_type(8))) short short8;   // 8 bf16 = 4 VGPR
typedef __attribute__((ext_vector_type(4))) float floatx4;  // MFMA acc

// ---------------------------------------------------------------------------
// Pipeline (all features bf16, accum fp32):
//   CSR build (count/scan/fill/dinv)
//   cvt_x:    x fp32 -> xb bf16 [N][64]
//   prep_wt:  all weights -> bf16 transposed [out_ch][in_ch]
//   gather1:  mean of xb[src] -> agg1b bf16 [N][64]
//   dense1:   h1 = relu(Ws1.xb + Wn1.agg1b + b1)       (MFMA) -> h1b [N][128]
//   t2:       t2 = h1 @ Wn2                            (MFMA) -> t2b [N][64]
//   gather2:  mean of t2b[src] -> agg2f fp32 [N][64]   (exact: aggregate after
//             linear transform == transform after aggregate)
//   dense2+cls: h2 = relu(Ws2.h1 + agg2 + b2); out = h2@wc + bc  (MFMA+LDS)
// ---------------------------------------------------------------------------

__device__ __forceinline__ unsigned short f2bf(float f) {  // RNE
    union { float f; unsigned u; } v; v.f = f;
    unsigned r = v.u + 0x7FFFu + ((v.u >> 16) & 1u);
    return (unsigned short)(r >> 16);
}
__device__ __forceinline__ float bflo(unsigned w) { return __uint_as_float(w << 16); }
__device__ __forceinline__ float bfhi(unsigned w) { return __uint_as_float(w & 0xFFFF0000u); }

// ---- CSR build ------------------------------------------------------------

__global__ __launch_bounds__(256) void count_kernel(
        const int* __restrict__ ei, int* __restrict__ deg)
{
    int e = blockIdx.x * 256 + threadIdx.x;
    if (e >= N_EDGES) return;
    atomicAdd(&deg[ei[N_EDGES + e]], 1);
}

__global__ __launch_bounds__(256) void scan1_kernel(
        const int* __restrict__ deg, int* __restrict__ part,
        int* __restrict__ bsum, int n)
{
    __shared__ int sd[256];
    int tid = threadIdx.x;
    int base = blockIdx.x * 1024 + tid * 4;
    int v0 = 0, v1 = 0, v2 = 0, v3 = 0;
    if (base + 0 < n) v0 = deg[base + 0];
    if (base + 1 < n) v1 = deg[base + 1];
    if (base + 2 < n) v2 = deg[base + 2];
    if (base + 3 < n) v3 = deg[base + 3];
    int i0 = v0, i1 = v0 + v1, i2 = i1 + v2, i3 = i2 + v3;
    sd[tid] = i3;
    __syncthreads();
    for (int off = 1; off < 256; off <<= 1) {
        int x = 0;
        if (tid >= off) x = sd[tid - off];
        __syncthreads();
        if (tid >= off) sd[tid] += x;
        __syncthreads();
    }
    int excl = sd[tid] - i3;
    if (base + 0 < n) part[base + 0] = excl;
    if (base + 1 < n) part[base + 1] = excl + i0;
    if (base + 2 < n) part[base + 2] = excl + i1;
    if (base + 3 < n) part[base + 3] = excl + i2;
    if (tid == 255) bsum[blockIdx.x] = sd[255];
}

__global__ __launch_bounds__(256) void scan2_kernel(int* __restrict__ bsum, int nb)
{
    __shared__ int sd[256];
    int tid = threadIdx.x;
    int v = (tid < nb) ? bsum[tid] : 0;
    sd[tid] = v;
    __syncthreads();
    for (int off = 1; off < 256; off <<= 1) {
        int x = 0;
        if (tid >= off) x = sd[tid - off];
        __syncthreads();
        if (tid >= off) sd[tid] += x;
        __syncthreads();
    }
    if (tid < nb) bsum[tid] = sd[tid] - v;
}

__global__ __launch_bounds__(256) void scan3_kernel(
        int* __restrict__ row_ptr, const int* __restrict__ bsum, int n)
{
    int i = blockIdx.x * 256 + threadIdx.x;
    if (i < n) row_ptr[i] += bsum[i >> 10];
    if (i == n) row_ptr[n] = N_EDGES;
}

__global__ __launch_bounds__(256) void fill_kernel(
        const int* __restrict__ ei, const int* __restrict__ row_ptr,
        int* __restrict__ cursor, int* __restrict__ sorted_src)
{
    int e = blockIdx.x * 256 + threadIdx.x;
    if (e >= N_EDGES) return;
    int src = ei[e];
    int dst = ei[N_EDGES + e];
    int pos = atomicAdd(&cursor[dst], 1);
    sorted_src[row_ptr[dst] + pos] = src;
}

__global__ __launch_bounds__(256) void dinv_kernel(
        const int* __restrict__ deg, float* __restrict__ dinv)
{
    int i = blockIdx.x * 256 + threadIdx.x;
    if (i < N_NODES) dinv[i] = 1.0f / (float)max(deg[i], 1);
}

// ---- conversions ----------------------------------------------------------

// x [N,64] fp32 -> bf16; one thread per 8 elements
__global__ __launch_bounds__(256) void cvt_x_kernel(
        const float* __restrict__ x, unsigned short* __restrict__ xb)
{
    int i = blockIdx.x * 256 + threadIdx.x;
    if (i >= N_NODES * 64 / 8) return;
    float4 a = ((const float4*)x)[(size_t)i * 2];
    float4 b = ((const float4*)x)[(size_t)i * 2 + 1];
    ushort4 r0, r1;
    r0.x = f2bf(a.x); r0.y = f2bf(a.y); r0.z = f2bf(a.z); r0.w = f2bf(a.w);
    r1.x = f2bf(b.x); r1.y = f2bf(b.y); r1.z = f2bf(b.z); r1.w = f2bf(b.w);
    ((ushort4*)xb)[(size_t)i * 2]     = r0;
    ((ushort4*)xb)[(size_t)i * 2 + 1] = r1;
}

// All weights -> bf16, transposed to [out_ch][in_ch]
__global__ __launch_bounds__(256) void prep_wt_kernel(
        const float* __restrict__ ws1, const float* __restrict__ wn1,   // [64][128]
        const float* __restrict__ ws2, const float* __restrict__ wn2,   // [128][64]
        unsigned short* __restrict__ wt1s, unsigned short* __restrict__ wt1n, // [128][64]
        unsigned short* __restrict__ wt2s, unsigned short* __restrict__ wt2n) // [64][128]
{
    int i = blockIdx.x * 256 + threadIdx.x;
    if (i < 8192) {                 // layer 1: WT[o][c] = W[c][o], o<128, c<64
        int o = i >> 6, c = i & 63;
        wt1s[i] = f2bf(ws1[c * 128 + o]);
        wt1n[i] = f2bf(wn1[c * 128 + o]);
    } else if (i < 16384) {         // layer 2: WT[o][c] = W[c][o], o<64, c<128
        int j = i - 8192;
        int o = j >> 7, c = j & 127;
        wt2s[j] = f2bf(ws2[c * 64 + o]);
        wt2n[j] = f2bf(wn2[c * 64 + o]);
    }
}

// ---- gather-mean over bf16 rows of 64 channels ---------------------------
// 8 threads/node, each owns 8 channels (16B). fp32 accumulate.
template<bool OUT_BF16>
__global__ __launch_bounds__(256) void gatherb_kernel(
        const int* __restrict__ row_ptr, const int* __restrict__ srcs,
        const unsigned short* __restrict__ featb,  // [N][64] bf16
        const float* __restrict__ dinv, void* __restrict__ aggp)
{
    int gid = blockIdx.x * 256 + threadIdx.x;
    int n = gid >> 3;
    int q = gid & 7;
    if (n >= N_NODES) return;
    int beg = row_ptr[n];
    int end = row_ptr[n + 1];
    const uint4* f4 = (const uint4*)featb;  // 16B = 8 bf16
    float a0=0,a1=0,a2=0,a3=0,a4=0,a5=0,a6=0,a7=0;
    for (int e = beg; e < end; ++e) {
        int s = srcs[e];
        uint4 v = f4[(size_t)s * 8 + q];
        a0 += bflo(v.x); a1 += bfhi(v.x);
        a2 += bflo(v.y); a3 += bfhi(v.y);
        a4 += bflo(v.z); a5 += bfhi(v.z);
        a6 += bflo(v.w); a7 += bfhi(v.w);
    }
    float di = dinv[n];
    a0*=di; a1*=di; a2*=di; a3*=di; a4*=di; a5*=di; a6*=di; a7*=di;
    if (OUT_BF16) {
        ushort4 r0, r1;
        r0.x=f2bf(a0); r0.y=f2bf(a1); r0.z=f2bf(a2); r0.w=f2bf(a3);
        r1.x=f2bf(a4); r1.y=f2bf(a5); r1.z=f2bf(a6); r1.w=f2bf(a7);
        ((ushort4*)aggp)[(size_t)n * 16 + q * 2]     = r0;
        ((ushort4*)aggp)[(size_t)n * 16 + q * 2 + 1] = r1;
    } else {
        float4 r0 = make_float4(a0,a1,a2,a3);
        float4 r1 = make_float4(a4,a5,a6,a7);
        ((float4*)aggp)[(size_t)n * 16 + q * 2]     = r0;
        ((float4*)aggp)[(size_t)n * 16 + q * 2 + 1] = r1;
    }
}

// ---- MFMA GEMMs -----------------------------------------------------------
// All computed as D[m=out_ch][n=node]: A = WT (och-major, ch-contig),
// B = feature rows (node-major, ch-contig). Per wave: 16 nodes, all och tiles.
// D layout (16x16x32): col(lane&15)=node, row(quad*4+reg)=och -> 8B bf16 store.

// dense1: h1 = relu(Ws1.x + Wn1.agg1 + b1), K=64, M=128
__global__ __launch_bounds__(256) void dense1_mfma(
        const unsigned short* __restrict__ xb,    // [N][64]
        const unsigned short* __restrict__ aggb,  // [N][64]
        const unsigned short* __restrict__ wts,   // [128][64]
        const unsigned short* __restrict__ wtn,   // [128][64]
        const float* __restrict__ bias,           // [128]
        unsigned short* __restrict__ h1b)         // [N][128]
{
    int lane = threadIdx.x & 63;
    int wv   = threadIdx.x >> 6;
    int quad = lane >> 4;
    int col  = lane & 15;
    int nl = blockIdx.x * 64 + wv * 16 + col;
    int nc = min(nl, N_NODES - 1);
    bool ok = nl < N_NODES;

    const short8 bs0 = *(const short8*)(xb   + (size_t)nc * 64 +      quad * 8);
    const short8 bs1 = *(const short8*)(xb   + (size_t)nc * 64 + 32 + quad * 8);
    const short8 bn0 = *(const short8*)(aggb + (size_t)nc * 64 +      quad * 8);
    const short8 bn1 = *(const short8*)(aggb + (size_t)nc * 64 + 32 + quad * 8);

#pragma unroll
    for (int mt = 0; mt < 8; ++mt) {
        int m = mt * 16 + col;
        const short8 as0 = *(const short8*)(wts + (size_t)m * 64 +      quad * 8);
        const short8 as1 = *(const short8*)(wts + (size_t)m * 64 + 32 + quad * 8);
        const short8 an0 = *(const short8*)(wtn + (size_t)m * 64 +      quad * 8);
        const short8 an1 = *(const short8*)(wtn + (size_t)m * 64 + 32 + quad * 8);
        floatx4 acc = {0.f, 0.f, 0.f, 0.f};
        acc = __builtin_amdgcn_mfma_f32_16x16x32_bf16(as0, bs0, acc, 0, 0, 0);
        acc = __builtin_amdgcn_mfma_f32_16x16x32_bf16(as1, bs1, acc, 0, 0, 0);
        acc = __builtin_amdgcn_mfma_f32_16x16x32_bf16(an0, bn0, acc, 0, 0, 0);
        acc = __builtin_amdgcn_mfma_f32_16x16x32_bf16(an1, bn1, acc, 0, 0, 0);
        if (ok) {
            int och = mt * 16 + quad * 4;
            float4 bv = *(const float4*)(bias + och);
            ushort4 r;
            r.x = f2bf(fmaxf(acc[0] + bv.x, 0.f));
            r.y = f2bf(fmaxf(acc[1] + bv.y, 0.f));
            r.z = f2bf(fmaxf(acc[2] + bv.z, 0.f));
            r.w = f2bf(fmaxf(acc[3] + bv.w, 0.f));
            *(ushort4*)(h1b + (size_t)nl * 128 + och) = r;
        }
    }
}

// t2 = h1 @ Wn2 (no bias/relu), K=128, M=64
__global__ __launch_bounds__(256) void t2_mfma(
        const unsigned short* __restrict__ h1b,  // [N][128]
        const unsigned short* __restrict__ wtn,  // [64][128]
        unsigned short* __restrict__ t2b)        // [N][64]
{
    int lane = threadIdx.x & 63;
    int wv   = threadIdx.x >> 6;
    int quad = lane >> 4;
    int col  = lane & 15;
    int nl = blockIdx.x * 64 + wv * 16 + col;
    int nc = min(nl, N_NODES - 1);
    bool ok = nl < N_NODES;

    short8 b[4];
#pragma unroll
    for (int kc = 0; kc < 4; ++kc)
        b[kc] = *(const short8*)(h1b + (size_t)nc * 128 + kc * 32 + quad * 8);

#pragma unroll
    for (int mt = 0; mt < 4; ++mt) {
        int m = mt * 16 + col;
        floatx4 acc = {0.f, 0.f, 0.f, 0.f};
#pragma unroll
        for (int kc = 0; kc < 4; ++kc) {
            const short8 a = *(const short8*)(wtn + (size_t)m * 128 + kc * 32 + quad * 8);
            acc = __builtin_amdgcn_mfma_f32_16x16x32_bf16(a, b[kc], acc, 0, 0, 0);
        }
        if (ok) {
            int och = mt * 16 + quad * 4;
            ushort4 r;
            r.x = f2bf(acc[0]); r.y = f2bf(acc[1]);
            r.z = f2bf(acc[2]); r.w = f2bf(acc[3]);
            *(ushort4*)(t2b + (size_t)nl * 64 + och) = r;
        }
    }
}

// dense2 + classifier: h2 = relu(Ws2.h1 + agg2 + b2); out = h2@wc + bc
__global__ __launch_bounds__(256) void dense2_cls_mfma(
        const unsigned short* __restrict__ h1b,  // [N][128]
        const unsigned short* __restrict__ wts,  // [64][128]
        const float* __restrict__ agg2,          // [N][64] fp32
        const float* __restrict__ b2,            // [64]
        const float* __restrict__ wc,            // [64][20]
        const float* __restrict__ bc,            // [20]
        float* __restrict__ out)                 // [N][20]
{
    __shared__ float hs[64][65];
    __shared__ float wcs[64 * N_CLS];
    __shared__ float bcs[N_CLS];

    int tid = threadIdx.x;
    int lane = tid & 63;
    int wv   = tid >> 6;
    int quad = lane >> 4;
    int col  = lane & 15;
    int node0 = blockIdx.x * 64;
    int nl = node0 + wv * 16 + col;
    int nc = min(nl, N_NODES - 1);

    for (int t = tid; t < 64 * N_CLS; t += 256) wcs[t] = wc[t];
    if (tid < N_CLS) bcs[tid] = bc[tid];

    short8 b[4];
#pragma unroll
    for (int kc = 0; kc < 4; ++kc)
        b[kc] = *(const short8*)(h1b + (size_t)nc * 128 + kc * 32 + quad * 8);

#pragma unroll
    for (int mt = 0; mt < 4; ++mt) {
        int m = mt * 16 + col;
        floatx4 acc = {0.f, 0.f, 0.f, 0.f};
#pragma unroll
        for (int kc = 0; kc < 4; ++kc) {
            const short8 a = *(const short8*)(wts + (size_t)m * 128 + kc * 32 + quad * 8);
            acc = __builtin_amdgcn_mfma_f32_16x16x32_bf16(a, b[kc], acc, 0, 0, 0);
        }
        int och = mt * 16 + quad * 4;
        float4 av = *(const float4*)(agg2 + (size_t)nc * 64 + och);
        float4 bv = *(const float4*)(b2 + och);
        hs[wv * 16 + col][och + 0] = fmaxf(acc[0] + av.x + bv.x, 0.f);
        hs[wv * 16 + col][och + 1] = fmaxf(acc[1] + av.y + bv.y, 0.f);
        hs[wv * 16 + col][och + 2] = fmaxf(acc[2] + av.z + bv.z, 0.f);
        hs[wv * 16 + col][och + 3] = fmaxf(acc[3] + av.w + bv.w, 0.f);
    }
    __syncthreads();

    for (int o = tid; o < 64 * N_CLS; o += 256) {
        int n = o / N_CLS, cls = o % N_CLS;
        if (node0 + n >= N_NODES) continue;
        float s = bcs[cls];
#pragma unroll
        for (int k = 0; k < 64; ++k) s += hs[n][k] * wcs[k * N_CLS + cls];
        out[(size_t)(node0 + n) * N_CLS + cls] = s;
    }
}

// ---------------------------------------------------------------------------

extern "C" void kernel_launch(void* const* d_in, const int* in_sizes, int n_in,
                              void* d_out, int out_size, void* d_ws, size_t ws_size,
                              hipStream_t stream)
{
    const float* x        = (const float*)d_in[0];
    const int*   ei       = (const int*)  d_in[1];
    const float* w_self1  = (const float*)d_in[2];
    const float* w_neigh1 = (const float*)d_in[3];
    const float* b1       = (const float*)d_in[4];
    const float* w_self2  = (const float*)d_in[5];
    const float* w_neigh2 = (const float*)d_in[6];
    const float* b2       = (const float*)d_in[7];
    const float* wc       = (const float*)d_in[8];
    const float* bc       = (const float*)d_in[9];
    float* out = (float*)d_out;

    const size_t N = N_NODES;
    int*   deg_i   = (int*)d_ws;
    int*   row_ptr = deg_i + N;            // N+8
    int*   cursor  = row_ptr + N + 8;
    int*   bsum    = cursor + N;           // 128
    int*   s_src   = bsum + 128;           // E
    float* dinv    = (float*)(s_src + N_EDGES);
    float* agg2f   = dinv + N;             // N x 64 fp32
    unsigned short* xb    = (unsigned short*)(agg2f + 64 * N);
    unsigned short* agg1b = xb + 64 * N;
    unsigned short* h1b   = agg1b + 64 * N;   // N x 128
    unsigned short* t2b   = h1b + 128 * N;    // N x 64
    unsigned short* wt1s  = t2b + 64 * N;     // 128x64
    unsigned short* wt1n  = wt1s + 8192;
    unsigned short* wt2s  = wt1n + 8192;      // 64x128
    unsigned short* wt2n  = wt2s + 8192;

    hipMemsetAsync(deg_i,  0, N * sizeof(int), stream);
    hipMemsetAsync(cursor, 0, N * sizeof(int), stream);

    const int EB = (N_EDGES + 255) / 256;          // 6250
    const int NB1024 = (N_NODES + 1023) / 1024;    // 98
    const int NB256  = (N_NODES + 256) / 256;      // 391 (covers i==N for scan3)
    const int GB = (N_NODES * 8) / 256;            // 3125
    const int MB = (N_NODES + 63) / 64;            // 1563

    cvt_x_kernel<<<(N_NODES * 64 / 8 + 255) / 256, 256, 0, stream>>>(x, xb);
    prep_wt_kernel<<<64, 256, 0, stream>>>(w_self1, w_neigh1, w_self2, w_neigh2,
                                           wt1s, wt1n, wt2s, wt2n);

    count_kernel<<<EB, 256, 0, stream>>>(ei, deg_i);
    scan1_kernel<<<NB1024, 256, 0, stream>>>(deg_i, row_ptr, bsum, N_NODES);
    scan2_kernel<<<1, 256, 0, stream>>>(bsum, NB1024);
    scan3_kernel<<<NB256, 256, 0, stream>>>(row_ptr, bsum, N_NODES);
    fill_kernel<<<EB, 256, 0, stream>>>(ei, row_ptr, cursor, s_src);
    dinv_kernel<<<NB256, 256, 0, stream>>>(deg_i, dinv);

    gatherb_kernel<true><<<GB, 256, 0, stream>>>(row_ptr, s_src, xb, dinv, agg1b);
    dense1_mfma<<<MB, 256, 0, stream>>>(xb, agg1b, wt1s, wt1n, b1, h1b);
    t2_mfma<<<MB, 256, 0, stream>>>(h1b, wt2n, t2b);
    gatherb_kernel<false><<<GB, 256, 0, stream>>>(row_ptr, s_src, t2b, dinv, agg2f);
    dense2_cls_mfma<<<MB, 256, 0, stream>>>(h1b, wt2s, agg2f, b2, wc, bc, out);
}

// Round 4
// 416.400 us; speedup vs baseline: 10.1741x; 1.1233x over previous
//
#include <hip/hip_runtime.h>

#define N_NODES 100000
#define N_EDGES 1600000
#define IN_C    64
#define HID_C   128
#define OUT_C   64
#define N_CLS   20

#define BUCKETS 196          // ceil(N_NODES / 512)
#define SLICES  64
#define CAP     256          // per (bucket,slice); mean fill 127.5, +11 sigma

typedef __attribute__((ext_vector_type(8))) short short8;   // 8 bf16 = 4 VGPR
typedef __attribute__((ext_vector_type(4))) float floatx4;  // MFMA acc

__device__ __forceinline__ unsigned short f2bf(float f) {  // RNE
    union { float f; unsigned u; } v; v.f = f;
    unsigned r = v.u + 0x7FFFu + ((v.u >> 16) & 1u);
    return (unsigned short)(r >> 16);
}
__device__ __forceinline__ float bflo(unsigned w) { return __uint_as_float(w << 16); }
__device__ __forceinline__ float bfhi(unsigned w) { return __uint_as_float(w & 0xFFFF0000u); }

// ---- CSR build: binned counting sort --------------------------------------
// Pass A: scatter packed edges into (bucket, slice) windows. slice=blockIdx&63
// keeps each window single-XCD (round-robin dispatch) -> full-line writebacks.
__global__ __launch_bounds__(256) void binA_kernel(
        const int* __restrict__ ei, int* __restrict__ bcnt,
        unsigned* __restrict__ bins)
{
    int e = blockIdx.x * 256 + threadIdx.x;
    if (e >= N_EDGES) return;
    int src = ei[e];
    int dst = ei[N_EDGES + e];
    int b  = dst >> 9;                       // 512 nodes per bucket
    int sl = blockIdx.x & (SLICES - 1);
    int w  = b * SLICES + sl;
    int pos = atomicAdd(&bcnt[w], 1);
    if (pos < CAP)                           // statistically unreachable
        bins[((unsigned)w << 8) + pos] = ((unsigned)(dst & 511) << 17) | (unsigned)src;
}

// Pass scan: bucket_base = exclusive scan of per-bucket totals.
__global__ __launch_bounds__(256) void bscan_kernel(
        const int* __restrict__ bcnt, int* __restrict__ bucket_base,
        int* __restrict__ row_ptr)
{
    __shared__ int sd[256];
    int t = threadIdx.x;
    int tot = 0;
    if (t < BUCKETS) {
        for (int sl = 0; sl < SLICES; ++sl)
            tot += min(bcnt[t * SLICES + sl], CAP);
    }
    sd[t] = tot;
    __syncthreads();
    for (int off = 1; off < 256; off <<= 1) {
        int x = 0;
        if (t >= off) x = sd[t - off];
        __syncthreads();
        if (t >= off) sd[t] += x;
        __syncthreads();
    }
    if (t < BUCKETS) bucket_base[t] = sd[t] - tot;
    if (t == 0) row_ptr[N_NODES] = N_EDGES;
}

// Pass B: one block per bucket. LDS-stage entries, histogram 512 local nodes,
// scan -> row_ptr + dinv, LDS-cursor scatter of src into the bucket's
// contiguous sorted_src window (single-CU window -> L2-merged writebacks).
__global__ __launch_bounds__(256) void buildB_kernel(
        const int* __restrict__ bcnt, const unsigned* __restrict__ bins,
        const int* __restrict__ bucket_base,
        int* __restrict__ row_ptr, int* __restrict__ sorted_src,
        float* __restrict__ dinv)
{
    __shared__ unsigned ent[SLICES * CAP];    // 64 KB
    __shared__ int scnt[SLICES], soff[SLICES];
    __shared__ int cnt[512], lofs[512], cur[512];
    __shared__ int sd[256];

    const int b   = blockIdx.x;
    const int tid = threadIdx.x;
    const int node0 = b * 512;

    if (tid < SLICES) scnt[tid] = min(bcnt[b * SLICES + tid], CAP);
    { int i = tid; cnt[i] = 0; cnt[i + 256] = 0; }
    __syncthreads();
    if (tid == 0) {
        int acc = 0;
        for (int sl = 0; sl < SLICES; ++sl) { soff[sl] = acc; acc += scnt[sl]; }
    }
    __syncthreads();

    // stage + histogram
    for (int sl = 0; sl < SLICES; ++sl) {
        int len = scnt[sl];
        const unsigned* seg = bins + (((unsigned)(b * SLICES + sl)) << 8);
        int base = soff[sl];
        for (int i = tid; i < len; i += 256) {
            unsigned e = seg[i];
            ent[base + i] = e;
            atomicAdd((unsigned*)&cnt[e >> 17], 1u);
        }
    }
    __syncthreads();
    const int T = soff[SLICES - 1] + scnt[SLICES - 1];

    // exclusive scan of cnt[512]: 2 elements per thread
    int a0 = cnt[2 * tid], a1 = cnt[2 * tid + 1];
    int s2 = a0 + a1;
    sd[tid] = s2;
    __syncthreads();
    for (int off = 1; off < 256; off <<= 1) {
        int x = 0;
        if (tid >= off) x = sd[tid - off];
        __syncthreads();
        if (tid >= off) sd[tid] += x;
        __syncthreads();
    }
    int excl = sd[tid] - s2;
    lofs[2 * tid]     = excl;
    lofs[2 * tid + 1] = excl + a0;
    cur[2 * tid]      = excl;
    cur[2 * tid + 1]  = excl + a0;
    __syncthreads();

    const int gbase = bucket_base[b];
    // row_ptr + dinv for this bucket's nodes
    for (int j = tid; j < 512; j += 256) {
        int node = node0 + j;
        if (node < N_NODES) {
            row_ptr[node] = gbase + lofs[j];
            dinv[node] = 1.0f / (float)max(cnt[j], 1);
        }
    }
    // scatter into the contiguous window
    for (int i = tid; i < T; i += 256) {
        unsigned e = ent[i];
        int dl = e >> 17;
        int p = atomicAdd((unsigned*)&cur[dl], 1u);
        sorted_src[gbase + p] = (int)(e & 0x1FFFFu);
    }
}

// ---- conversions ----------------------------------------------------------

__global__ __launch_bounds__(256) void cvt_x_kernel(
        const float* __restrict__ x, unsigned short* __restrict__ xb)
{
    int i = blockIdx.x * 256 + threadIdx.x;
    if (i >= N_NODES * 64 / 8) return;
    float4 a = ((const float4*)x)[(size_t)i * 2];
    float4 b = ((const float4*)x)[(size_t)i * 2 + 1];
    ushort4 r0, r1;
    r0.x = f2bf(a.x); r0.y = f2bf(a.y); r0.z = f2bf(a.z); r0.w = f2bf(a.w);
    r1.x = f2bf(b.x); r1.y = f2bf(b.y); r1.z = f2bf(b.z); r1.w = f2bf(b.w);
    ((ushort4*)xb)[(size_t)i * 2]     = r0;
    ((ushort4*)xb)[(size_t)i * 2 + 1] = r1;
}

__global__ __launch_bounds__(256) void prep_wt_kernel(
        const float* __restrict__ ws1, const float* __restrict__ wn1,   // [64][128]
        const float* __restrict__ ws2, const float* __restrict__ wn2,   // [128][64]
        unsigned short* __restrict__ wt1s, unsigned short* __restrict__ wt1n, // [128][64]
        unsigned short* __restrict__ wt2s, unsigned short* __restrict__ wt2n) // [64][128]
{
    int i = blockIdx.x * 256 + threadIdx.x;
    if (i < 8192) {
        int o = i >> 6, c = i & 63;
        wt1s[i] = f2bf(ws1[c * 128 + o]);
        wt1n[i] = f2bf(wn1[c * 128 + o]);
    } else if (i < 16384) {
        int j = i - 8192;
        int o = j >> 7, c = j & 127;
        wt2s[j] = f2bf(ws2[c * 64 + o]);
        wt2n[j] = f2bf(wn2[c * 64 + o]);
    }
}

// ---- gather-mean over bf16 rows of 64 channels ---------------------------
__global__ __launch_bounds__(256) void gatherb_kernel(
        const int* __restrict__ row_ptr, const int* __restrict__ srcs,
        const unsigned short* __restrict__ featb,  // [N][64] bf16
        const float* __restrict__ dinv, unsigned short* __restrict__ aggb)
{
    int gid = blockIdx.x * 256 + threadIdx.x;
    int n = gid >> 3;
    int q = gid & 7;
    if (n >= N_NODES) return;
    int beg = row_ptr[n];
    int end = row_ptr[n + 1];
    const uint4* f4 = (const uint4*)featb;
    float a0=0,a1=0,a2=0,a3=0,a4=0,a5=0,a6=0,a7=0;
    for (int e = beg; e < end; ++e) {
        int s = srcs[e];
        uint4 v = f4[(size_t)s * 8 + q];
        a0 += bflo(v.x); a1 += bfhi(v.x);
        a2 += bflo(v.y); a3 += bfhi(v.y);
        a4 += bflo(v.z); a5 += bfhi(v.z);
        a6 += bflo(v.w); a7 += bfhi(v.w);
    }
    float di = dinv[n];
    ushort4 r0, r1;
    r0.x=f2bf(a0*di); r0.y=f2bf(a1*di); r0.z=f2bf(a2*di); r0.w=f2bf(a3*di);
    r1.x=f2bf(a4*di); r1.y=f2bf(a5*di); r1.z=f2bf(a6*di); r1.w=f2bf(a7*di);
    ((ushort4*)aggb)[(size_t)n * 16 + q * 2]     = r0;
    ((ushort4*)aggb)[(size_t)n * 16 + q * 2 + 1] = r1;
}

// ---- MFMA GEMMs (D[m=out_ch][n=node], see round-3 notes) ------------------

__global__ __launch_bounds__(256) void dense1_mfma(
        const unsigned short* __restrict__ xb,    // [N][64]
        const unsigned short* __restrict__ aggb,  // [N][64]
        const unsigned short* __restrict__ wts,   // [128][64]
        const unsigned short* __restrict__ wtn,   // [128][64]
        const float* __restrict__ bias,           // [128]
        unsigned short* __restrict__ h1b)         // [N][128]
{
    int lane = threadIdx.x & 63;
    int wv   = threadIdx.x >> 6;
    int quad = lane >> 4;
    int col  = lane & 15;
    int nl = blockIdx.x * 64 + wv * 16 + col;
    int nc = min(nl, N_NODES - 1);
    bool ok = nl < N_NODES;

    const short8 bs0 = *(const short8*)(xb   + (size_t)nc * 64 +      quad * 8);
    const short8 bs1 = *(const short8*)(xb   + (size_t)nc * 64 + 32 + quad * 8);
    const short8 bn0 = *(const short8*)(aggb + (size_t)nc * 64 +      quad * 8);
    const short8 bn1 = *(const short8*)(aggb + (size_t)nc * 64 + 32 + quad * 8);

#pragma unroll
    for (int mt = 0; mt < 8; ++mt) {
        int m = mt * 16 + col;
        const short8 as0 = *(const short8*)(wts + (size_t)m * 64 +      quad * 8);
        const short8 as1 = *(const short8*)(wts + (size_t)m * 64 + 32 + quad * 8);
        const short8 an0 = *(const short8*)(wtn + (size_t)m * 64 +      quad * 8);
        const short8 an1 = *(const short8*)(wtn + (size_t)m * 64 + 32 + quad * 8);
        floatx4 acc = {0.f, 0.f, 0.f, 0.f};
        acc = __builtin_amdgcn_mfma_f32_16x16x32_bf16(as0, bs0, acc, 0, 0, 0);
        acc = __builtin_amdgcn_mfma_f32_16x16x32_bf16(as1, bs1, acc, 0, 0, 0);
        acc = __builtin_amdgcn_mfma_f32_16x16x32_bf16(an0, bn0, acc, 0, 0, 0);
        acc = __builtin_amdgcn_mfma_f32_16x16x32_bf16(an1, bn1, acc, 0, 0, 0);
        if (ok) {
            int och = mt * 16 + quad * 4;
            float4 bv = *(const float4*)(bias + och);
            ushort4 r;
            r.x = f2bf(fmaxf(acc[0] + bv.x, 0.f));
            r.y = f2bf(fmaxf(acc[1] + bv.y, 0.f));
            r.z = f2bf(fmaxf(acc[2] + bv.z, 0.f));
            r.w = f2bf(fmaxf(acc[3] + bv.w, 0.f));
            *(ushort4*)(h1b + (size_t)nl * 128 + och) = r;
        }
    }
}

__global__ __launch_bounds__(256) void t2_mfma(
        const unsigned short* __restrict__ h1b,  // [N][128]
        const unsigned short* __restrict__ wtn,  // [64][128]
        unsigned short* __restrict__ t2b)        // [N][64]
{
    int lane = threadIdx.x & 63;
    int wv   = threadIdx.x >> 6;
    int quad = lane >> 4;
    int col  = lane & 15;
    int nl = blockIdx.x * 64 + wv * 16 + col;
    int nc = min(nl, N_NODES - 1);
    bool ok = nl < N_NODES;

    short8 b[4];
#pragma unroll
    for (int kc = 0; kc < 4; ++kc)
        b[kc] = *(const short8*)(h1b + (size_t)nc * 128 + kc * 32 + quad * 8);

#pragma unroll
    for (int mt = 0; mt < 4; ++mt) {
        int m = mt * 16 + col;
        floatx4 acc = {0.f, 0.f, 0.f, 0.f};
#pragma unroll
        for (int kc = 0; kc < 4; ++kc) {
            const short8 a = *(const short8*)(wtn + (size_t)m * 128 + kc * 32 + quad * 8);
            acc = __builtin_amdgcn_mfma_f32_16x16x32_bf16(a, b[kc], acc, 0, 0, 0);
        }
        if (ok) {
            int och = mt * 16 + quad * 4;
            ushort4 r;
            r.x = f2bf(acc[0]); r.y = f2bf(acc[1]);
            r.z = f2bf(acc[2]); r.w = f2bf(acc[3]);
            *(ushort4*)(t2b + (size_t)nl * 64 + och) = r;
        }
    }
}

__global__ __launch_bounds__(256) void dense2_cls_mfma(
        const unsigned short* __restrict__ h1b,   // [N][128]
        const unsigned short* __restrict__ wts,   // [64][128]
        const unsigned short* __restrict__ agg2b, // [N][64] bf16
        const float* __restrict__ b2,             // [64]
        const float* __restrict__ wc,             // [64][20]
        const float* __restrict__ bc,             // [20]
        float* __restrict__ out)                  // [N][20]
{
    __shared__ float hs[64][65];
    __shared__ float wcs[64 * N_CLS];
    __shared__ float bcs[N_CLS];

    int tid = threadIdx.x;
    int lane = tid & 63;
    int wv   = tid >> 6;
    int quad = lane >> 4;
    int col  = lane & 15;
    int node0 = blockIdx.x * 64;
    int nl = node0 + wv * 16 + col;
    int nc = min(nl, N_NODES - 1);

    for (int t = tid; t < 64 * N_CLS; t += 256) wcs[t] = wc[t];
    if (tid < N_CLS) bcs[tid] = bc[tid];

    short8 b[4];
#pragma unroll
    for (int kc = 0; kc < 4; ++kc)
        b[kc] = *(const short8*)(h1b + (size_t)nc * 128 + kc * 32 + quad * 8);

#pragma unroll
    for (int mt = 0; mt < 4; ++mt) {
        int m = mt * 16 + col;
        floatx4 acc = {0.f, 0.f, 0.f, 0.f};
#pragma unroll
        for (int kc = 0; kc < 4; ++kc) {
            const short8 a = *(const short8*)(wts + (size_t)m * 128 + kc * 32 + quad * 8);
            acc = __builtin_amdgcn_mfma_f32_16x16x32_bf16(a, b[kc], acc, 0, 0, 0);
        }
        int och = mt * 16 + quad * 4;
        ushort4 au = *(const ushort4*)(agg2b + (size_t)nc * 64 + och);
        float4 bv = *(const float4*)(b2 + och);
        hs[wv * 16 + col][och + 0] = fmaxf(acc[0] + bflo((unsigned)au.x << 16 >> 16 | ((unsigned)au.x << 16 & 0)) + 0.f, 0.f); // placeholder
        hs[wv * 16 + col][och + 0] = fmaxf(acc[0] + __uint_as_float((unsigned)au.x << 16) + bv.x, 0.f);
        hs[wv * 16 + col][och + 1] = fmaxf(acc[1] + __uint_as_float((unsigned)au.y << 16) + bv.y, 0.f);
        hs[wv * 16 + col][och + 2] = fmaxf(acc[2] + __uint_as_float((unsigned)au.z << 16) + bv.z, 0.f);
        hs[wv * 16 + col][och + 3] = fmaxf(acc[3] + __uint_as_float((unsigned)au.w << 16) + bv.w, 0.f);
    }
    __syncthreads();

    for (int o = tid; o < 64 * N_CLS; o += 256) {
        int n = o / N_CLS, cls = o % N_CLS;
        if (node0 + n >= N_NODES) continue;
        float s = bcs[cls];
#pragma unroll
        for (int k = 0; k < 64; ++k) s += hs[n][k] * wcs[k * N_CLS + cls];
        out[(size_t)(node0 + n) * N_CLS + cls] = s;
    }
}

// ---------------------------------------------------------------------------

extern "C" void kernel_launch(void* const* d_in, const int* in_sizes, int n_in,
                              void* d_out, int out_size, void* d_ws, size_t ws_size,
                              hipStream_t stream)
{
    const float* x        = (const float*)d_in[0];
    const int*   ei       = (const int*)  d_in[1];
    const float* w_self1  = (const float*)d_in[2];
    const float* w_neigh1 = (const float*)d_in[3];
    const float* b1       = (const float*)d_in[4];
    const float* w_self2  = (const float*)d_in[5];
    const float* w_neigh2 = (const float*)d_in[6];
    const float* b2       = (const float*)d_in[7];
    const float* wc       = (const float*)d_in[8];
    const float* bc       = (const float*)d_in[9];
    float* out = (float*)d_out;

    const size_t N = N_NODES;
    int*      bcnt    = (int*)d_ws;                       // BUCKETS*SLICES
    int*      bbase   = bcnt + BUCKETS * SLICES;          // 200
    int*      row_ptr = bbase + 200;                      // N+8
    unsigned* bins    = (unsigned*)(row_ptr + N + 8);     // BUCKETS*SLICES*CAP
    int*      s_src   = (int*)(bins + BUCKETS * SLICES * CAP);  // E
    float*    dinv    = (float*)(s_src + N_EDGES);        // N
    unsigned short* xb    = (unsigned short*)(dinv + N);
    unsigned short* agg1b = xb + 64 * N;
    unsigned short* h1b   = agg1b + 64 * N;               // N x 128
    unsigned short* t2b   = h1b + 128 * N;                // N x 64
    unsigned short* agg2b = t2b + 64 * N;                 // N x 64
    unsigned short* wt1s  = agg2b + 64 * N;               // 128x64
    unsigned short* wt1n  = wt1s + 8192;
    unsigned short* wt2s  = wt1n + 8192;                  // 64x128
    unsigned short* wt2n  = wt2s + 8192;

    hipMemsetAsync(bcnt, 0, BUCKETS * SLICES * sizeof(int), stream);

    const int EB = (N_EDGES + 255) / 256;          // 6250
    const int GB = (N_NODES * 8) / 256;            // 3125
    const int MB = (N_NODES + 63) / 64;            // 1563

    cvt_x_kernel<<<(N_NODES * 64 / 8 + 255) / 256, 256, 0, stream>>>(x, xb);
    prep_wt_kernel<<<64, 256, 0, stream>>>(w_self1, w_neigh1, w_self2, w_neigh2,
                                           wt1s, wt1n, wt2s, wt2n);

    binA_kernel<<<EB, 256, 0, stream>>>(ei, bcnt, bins);
    bscan_kernel<<<1, 256, 0, stream>>>(bcnt, bbase, row_ptr);
    buildB_kernel<<<BUCKETS, 256, 0, stream>>>(bcnt, bins, bbase,
                                               row_ptr, s_src, dinv);

    gatherb_kernel<<<GB, 256, 0, stream>>>(row_ptr, s_src, xb, dinv, agg1b);
    dense1_mfma<<<MB, 256, 0, stream>>>(xb, agg1b, wt1s, wt1n, b1, h1b);
    t2_mfma<<<MB, 256, 0, stream>>>(h1b, wt2n, t2b);
    gatherb_kernel<<<GB, 256, 0, stream>>>(row_ptr, s_src, t2b, dinv, agg2b);
    dense2_cls_mfma<<<MB, 256, 0, stream>>>(h1b, wt2s, agg2b, b2, wc, bc, out);
}

// Round 5
// 338.699 us; speedup vs baseline: 12.5081x; 1.2294x over previous
//
#include <hip/hip_runtime.h>

#define N_NODES 100000
#define N_EDGES 1600000
#define IN_C    64
#define HID_C   128
#define OUT_C   64
#define N_CLS   20

#define BUCKETS 196          // ceil(N_NODES / 512), 512 nodes per bucket
#define XSL     8            // one slice per XCD (blockIdx & 7)
#define WCAP    2560         // per (bucket,xcd) window; mean 1020, huge margin
#define EPB     4096         // edges per binA block
#define CAPB    44           // per-block per-bucket LDS cap; mean 20.9, +5sig,
                             // overflow -> correct (slow) global fallback

typedef __attribute__((ext_vector_type(8))) short short8;   // 8 bf16 = 4 VGPR
typedef __attribute__((ext_vector_type(4))) float floatx4;  // MFMA acc

__device__ __forceinline__ unsigned short f2bf(float f) {  // RNE
    union { float f; unsigned u; } v; v.f = f;
    unsigned r = v.u + 0x7FFFu + ((v.u >> 16) & 1u);
    return (unsigned short)(r >> 16);
}
__device__ __forceinline__ float bflo(unsigned w) { return __uint_as_float(w << 16); }
__device__ __forceinline__ float bfhi(unsigned w) { return __uint_as_float(w & 0xFFFF0000u); }

// ---- CSR build: binned counting sort --------------------------------------
// Pass A: block-local LDS binning, then one global atomic per (block,bucket)
// to reserve a contiguous run in the (bucket, xcd) window, then a coalesced
// flush of the bucket-sorted compacted entries. Per-edge global atomics only
// on (statistically unreachable) LDS overflow.
__global__ __launch_bounds__(256) void binA_kernel(
        const int* __restrict__ ei, int* __restrict__ bcnt,
        unsigned* __restrict__ bins)
{
    __shared__ unsigned lbins[BUCKETS * CAPB];   // 34.5 KB
    __shared__ unsigned comp[EPB];               // 16 KB
    __shared__ unsigned dsti[EPB];               // 16 KB
    __shared__ int lcnt[BUCKETS], lofs[BUCKETS], gb[BUCKETS];
    __shared__ int sd[256];

    const int tid = threadIdx.x;
    const int xcd = blockIdx.x & (XSL - 1);
    const int e0  = blockIdx.x * EPB;

    for (int w = tid; w < BUCKETS; w += 256) lcnt[w] = 0;
    __syncthreads();

    // phase 1: bin 4096 edges into LDS
    for (int it = 0; it < EPB / 256; ++it) {
        int e = e0 + it * 256 + tid;
        if (e >= N_EDGES) break;
        int src = ei[e];
        int dst = ei[N_EDGES + e];
        int b = dst >> 9;
        unsigned pk = ((unsigned)(dst & 511) << 17) | (unsigned)src;
        int pos = atomicAdd(&lcnt[b], 1);
        if (pos < CAPB) {
            lbins[b * CAPB + pos] = pk;
        } else {  // rare fallback: direct global append (always correct)
            int gp = atomicAdd(&bcnt[b * XSL + xcd], 1);
            if (gp < WCAP)
                bins[(unsigned)(b * XSL + xcd) * WCAP + gp] = pk;
        }
    }
    __syncthreads();

    // phase 2: exclusive scan of per-bucket counts (clamped to CAPB)
    int c = (tid < BUCKETS) ? min(lcnt[tid], CAPB) : 0;
    sd[tid] = c;
    __syncthreads();
    for (int off = 1; off < 256; off <<= 1) {
        int x = 0;
        if (tid >= off) x = sd[tid - off];
        __syncthreads();
        if (tid >= off) sd[tid] += x;
        __syncthreads();
    }
    if (tid < BUCKETS) lofs[tid] = sd[tid] - c;
    __syncthreads();
    const int T = sd[255];

    // phase 3: one global reservation per bucket
    if (tid < BUCKETS) {
        int cw = min(lcnt[tid], CAPB);
        gb[tid] = (cw > 0) ? atomicAdd(&bcnt[tid * XSL + xcd], cw) : 0;
    }
    __syncthreads();

    // phase 4: compact LDS bins (bucket-sorted) + precompute dest indices
    if (tid < BUCKETS) {
        int cw = min(lcnt[tid], CAPB);
        int lo = lofs[tid];
        unsigned wb = (unsigned)(tid * XSL + xcd) * WCAP + (unsigned)gb[tid];
        for (int i = 0; i < cw; ++i) {
            comp[lo + i] = lbins[tid * CAPB + i];
            dsti[lo + i] = wb + i;
        }
    }
    __syncthreads();

    // phase 5: coalesced-ish flush (addresses sorted, contiguous runs)
    for (int i = tid; i < T; i += 256)
        bins[dsti[i]] = comp[i];
}

// Pass scan: bucket_base = exclusive scan of per-bucket totals.
__global__ __launch_bounds__(256) void bscan_kernel(
        const int* __restrict__ bcnt, int* __restrict__ bucket_base,
        int* __restrict__ row_ptr)
{
    __shared__ int sd[256];
    int t = threadIdx.x;
    int tot = 0;
    if (t < BUCKETS) {
        for (int sl = 0; sl < XSL; ++sl)
            tot += min(bcnt[t * XSL + sl], WCAP);
    }
    sd[t] = tot;
    __syncthreads();
    for (int off = 1; off < 256; off <<= 1) {
        int x = 0;
        if (t >= off) x = sd[t - off];
        __syncthreads();
        if (t >= off) sd[t] += x;
        __syncthreads();
    }
    if (t < BUCKETS) bucket_base[t] = sd[t] - tot;
    if (t == 0) row_ptr[N_NODES] = N_EDGES;
}

// Pass B: one block per bucket. LDS-stage entries, histogram 512 local nodes,
// scan -> row_ptr + dinv, LDS-cursor scatter of src into the bucket's
// contiguous sorted_src window.
__global__ __launch_bounds__(256) void buildB_kernel(
        const int* __restrict__ bcnt, const unsigned* __restrict__ bins,
        const int* __restrict__ bucket_base,
        int* __restrict__ row_ptr, int* __restrict__ sorted_src,
        float* __restrict__ dinv)
{
    __shared__ unsigned ent[16384];           // 64 KB; mean fill 8163
    __shared__ int scnt[XSL], soff[XSL];
    __shared__ int cnt[512], lofs[512], cur[512];
    __shared__ int sd[256];

    const int b   = blockIdx.x;
    const int tid = threadIdx.x;
    const int node0 = b * 512;

    if (tid < XSL) scnt[tid] = min(bcnt[b * XSL + tid], WCAP);
    { int i = tid; cnt[i] = 0; cnt[i + 256] = 0; }
    __syncthreads();
    if (tid == 0) {
        int acc = 0;
        for (int sl = 0; sl < XSL; ++sl) {
            soff[sl] = acc;
            acc += scnt[sl];
            if (acc > 16384) { scnt[sl] -= (acc - 16384); acc = 16384; } // unreachable
        }
    }
    __syncthreads();

    // stage + histogram
    for (int sl = 0; sl < XSL; ++sl) {
        int len = scnt[sl];
        const unsigned* seg = bins + (unsigned)(b * XSL + sl) * WCAP;
        int base = soff[sl];
        for (int i = tid; i < len; i += 256) {
            unsigned e = seg[i];
            ent[base + i] = e;
            atomicAdd((unsigned*)&cnt[e >> 17], 1u);
        }
    }
    __syncthreads();
    const int T = soff[XSL - 1] + scnt[XSL - 1];

    // exclusive scan of cnt[512]: 2 elements per thread
    int a0 = cnt[2 * tid], a1 = cnt[2 * tid + 1];
    int s2 = a0 + a1;
    sd[tid] = s2;
    __syncthreads();
    for (int off = 1; off < 256; off <<= 1) {
        int x = 0;
        if (tid >= off) x = sd[tid - off];
        __syncthreads();
        if (tid >= off) sd[tid] += x;
        __syncthreads();
    }
    int excl = sd[tid] - s2;
    lofs[2 * tid]     = excl;
    lofs[2 * tid + 1] = excl + a0;
    cur[2 * tid]      = excl;
    cur[2 * tid + 1]  = excl + a0;
    __syncthreads();

    const int gbase = bucket_base[b];
    for (int j = tid; j < 512; j += 256) {
        int node = node0 + j;
        if (node < N_NODES) {
            row_ptr[node] = gbase + lofs[j];
            dinv[node] = 1.0f / (float)max(cnt[j], 1);
        }
    }
    for (int i = tid; i < T; i += 256) {
        unsigned e = ent[i];
        int dl = e >> 17;
        int p = atomicAdd((unsigned*)&cur[dl], 1u);
        sorted_src[gbase + p] = (int)(e & 0x1FFFFu);
    }
}

// ---- conversions ----------------------------------------------------------

__global__ __launch_bounds__(256) void cvt_x_kernel(
        const float* __restrict__ x, unsigned short* __restrict__ xb)
{
    int i = blockIdx.x * 256 + threadIdx.x;
    if (i >= N_NODES * 64 / 8) return;
    float4 a = ((const float4*)x)[(size_t)i * 2];
    float4 b = ((const float4*)x)[(size_t)i * 2 + 1];
    ushort4 r0, r1;
    r0.x = f2bf(a.x); r0.y = f2bf(a.y); r0.z = f2bf(a.z); r0.w = f2bf(a.w);
    r1.x = f2bf(b.x); r1.y = f2bf(b.y); r1.z = f2bf(b.z); r1.w = f2bf(b.w);
    ((ushort4*)xb)[(size_t)i * 2]     = r0;
    ((ushort4*)xb)[(size_t)i * 2 + 1] = r1;
}

__global__ __launch_bounds__(256) void prep_wt_kernel(
        const float* __restrict__ ws1, const float* __restrict__ wn1,   // [64][128]
        const float* __restrict__ ws2, const float* __restrict__ wn2,   // [128][64]
        unsigned short* __restrict__ wt1s, unsigned short* __restrict__ wt1n, // [128][64]
        unsigned short* __restrict__ wt2s, unsigned short* __restrict__ wt2n) // [64][128]
{
    int i = blockIdx.x * 256 + threadIdx.x;
    if (i < 8192) {
        int o = i >> 6, c = i & 63;
        wt1s[i] = f2bf(ws1[c * 128 + o]);
        wt1n[i] = f2bf(wn1[c * 128 + o]);
    } else if (i < 16384) {
        int j = i - 8192;
        int o = j >> 7, c = j & 127;
        wt2s[j] = f2bf(ws2[c * 64 + o]);
        wt2n[j] = f2bf(wn2[c * 64 + o]);
    }
}

// ---- gather-mean over bf16 rows of 64 channels ---------------------------
__global__ __launch_bounds__(256) void gatherb_kernel(
        const int* __restrict__ row_ptr, const int* __restrict__ srcs,
        const unsigned short* __restrict__ featb,  // [N][64] bf16
        const float* __restrict__ dinv, unsigned short* __restrict__ aggb)
{
    int gid = blockIdx.x * 256 + threadIdx.x;
    int n = gid >> 3;
    int q = gid & 7;
    if (n >= N_NODES) return;
    int beg = row_ptr[n];
    int end = row_ptr[n + 1];
    const uint4* f4 = (const uint4*)featb;
    float a0=0,a1=0,a2=0,a3=0,a4=0,a5=0,a6=0,a7=0;
    for (int e = beg; e < end; ++e) {
        int s = srcs[e];
        uint4 v = f4[(size_t)s * 8 + q];
        a0 += bflo(v.x); a1 += bfhi(v.x);
        a2 += bflo(v.y); a3 += bfhi(v.y);
        a4 += bflo(v.z); a5 += bfhi(v.z);
        a6 += bflo(v.w); a7 += bfhi(v.w);
    }
    float di = dinv[n];
    ushort4 r0, r1;
    r0.x=f2bf(a0*di); r0.y=f2bf(a1*di); r0.z=f2bf(a2*di); r0.w=f2bf(a3*di);
    r1.x=f2bf(a4*di); r1.y=f2bf(a5*di); r1.z=f2bf(a6*di); r1.w=f2bf(a7*di);
    ((ushort4*)aggb)[(size_t)n * 16 + q * 2]     = r0;
    ((ushort4*)aggb)[(size_t)n * 16 + q * 2 + 1] = r1;
}

// ---- MFMA GEMMs (D[m=out_ch][n=node]) -------------------------------------

__global__ __launch_bounds__(256) void dense1_mfma(
        const unsigned short* __restrict__ xb,    // [N][64]
        const unsigned short* __restrict__ aggb,  // [N][64]
        const unsigned short* __restrict__ wts,   // [128][64]
        const unsigned short* __restrict__ wtn,   // [128][64]
        const float* __restrict__ bias,           // [128]
        unsigned short* __restrict__ h1b)         // [N][128]
{
    int lane = threadIdx.x & 63;
    int wv   = threadIdx.x >> 6;
    int quad = lane >> 4;
    int col  = lane & 15;
    int nl = blockIdx.x * 64 + wv * 16 + col;
    int nc = min(nl, N_NODES - 1);
    bool ok = nl < N_NODES;

    const short8 bs0 = *(const short8*)(xb   + (size_t)nc * 64 +      quad * 8);
    const short8 bs1 = *(const short8*)(xb   + (size_t)nc * 64 + 32 + quad * 8);
    const short8 bn0 = *(const short8*)(aggb + (size_t)nc * 64 +      quad * 8);
    const short8 bn1 = *(const short8*)(aggb + (size_t)nc * 64 + 32 + quad * 8);

#pragma unroll
    for (int mt = 0; mt < 8; ++mt) {
        int m = mt * 16 + col;
        const short8 as0 = *(const short8*)(wts + (size_t)m * 64 +      quad * 8);
        const short8 as1 = *(const short8*)(wts + (size_t)m * 64 + 32 + quad * 8);
        const short8 an0 = *(const short8*)(wtn + (size_t)m * 64 +      quad * 8);
        const short8 an1 = *(const short8*)(wtn + (size_t)m * 64 + 32 + quad * 8);
        floatx4 acc = {0.f, 0.f, 0.f, 0.f};
        acc = __builtin_amdgcn_mfma_f32_16x16x32_bf16(as0, bs0, acc, 0, 0, 0);
        acc = __builtin_amdgcn_mfma_f32_16x16x32_bf16(as1, bs1, acc, 0, 0, 0);
        acc = __builtin_amdgcn_mfma_f32_16x16x32_bf16(an0, bn0, acc, 0, 0, 0);
        acc = __builtin_amdgcn_mfma_f32_16x16x32_bf16(an1, bn1, acc, 0, 0, 0);
        if (ok) {
            int och = mt * 16 + quad * 4;
            float4 bv = *(const float4*)(bias + och);
            ushort4 r;
            r.x = f2bf(fmaxf(acc[0] + bv.x, 0.f));
            r.y = f2bf(fmaxf(acc[1] + bv.y, 0.f));
            r.z = f2bf(fmaxf(acc[2] + bv.z, 0.f));
            r.w = f2bf(fmaxf(acc[3] + bv.w, 0.f));
            *(ushort4*)(h1b + (size_t)nl * 128 + och) = r;
        }
    }
}

__global__ __launch_bounds__(256) void t2_mfma(
        const unsigned short* __restrict__ h1b,  // [N][128]
        const unsigned short* __restrict__ wtn,  // [64][128]
        unsigned short* __restrict__ t2b)        // [N][64]
{
    int lane = threadIdx.x & 63;
    int wv   = threadIdx.x >> 6;
    int quad = lane >> 4;
    int col  = lane & 15;
    int nl = blockIdx.x * 64 + wv * 16 + col;
    int nc = min(nl, N_NODES - 1);
    bool ok = nl < N_NODES;

    short8 b[4];
#pragma unroll
    for (int kc = 0; kc < 4; ++kc)
        b[kc] = *(const short8*)(h1b + (size_t)nc * 128 + kc * 32 + quad * 8);

#pragma unroll
    for (int mt = 0; mt < 4; ++mt) {
        int m = mt * 16 + col;
        floatx4 acc = {0.f, 0.f, 0.f, 0.f};
#pragma unroll
        for (int kc = 0; kc < 4; ++kc) {
            const short8 a = *(const short8*)(wtn + (size_t)m * 128 + kc * 32 + quad * 8);
            acc = __builtin_amdgcn_mfma_f32_16x16x32_bf16(a, b[kc], acc, 0, 0, 0);
        }
        if (ok) {
            int och = mt * 16 + quad * 4;
            ushort4 r;
            r.x = f2bf(acc[0]); r.y = f2bf(acc[1]);
            r.z = f2bf(acc[2]); r.w = f2bf(acc[3]);
            *(ushort4*)(t2b + (size_t)nl * 64 + och) = r;
        }
    }
}

__global__ __launch_bounds__(256) void dense2_cls_mfma(
        const unsigned short* __restrict__ h1b,   // [N][128]
        const unsigned short* __restrict__ wts,   // [64][128]
        const unsigned short* __restrict__ agg2b, // [N][64] bf16
        const float* __restrict__ b2,             // [64]
        const float* __restrict__ wc,             // [64][20]
        const float* __restrict__ bc,             // [20]
        float* __restrict__ out)                  // [N][20]
{
    __shared__ float hs[64][65];
    __shared__ float wcs[64 * N_CLS];
    __shared__ float bcs[N_CLS];

    int tid = threadIdx.x;
    int lane = tid & 63;
    int wv   = tid >> 6;
    int quad = lane >> 4;
    int col  = lane & 15;
    int node0 = blockIdx.x * 64;
    int nl = node0 + wv * 16 + col;
    int nc = min(nl, N_NODES - 1);

    for (int t = tid; t < 64 * N_CLS; t += 256) wcs[t] = wc[t];
    if (tid < N_CLS) bcs[tid] = bc[tid];

    short8 b[4];
#pragma unroll
    for (int kc = 0; kc < 4; ++kc)
        b[kc] = *(const short8*)(h1b + (size_t)nc * 128 + kc * 32 + quad * 8);

#pragma unroll
    for (int mt = 0; mt < 4; ++mt) {
        int m = mt * 16 + col;
        floatx4 acc = {0.f, 0.f, 0.f, 0.f};
#pragma unroll
        for (int kc = 0; kc < 4; ++kc) {
            const short8 a = *(const short8*)(wts + (size_t)m * 128 + kc * 32 + quad * 8);
            acc = __builtin_amdgcn_mfma_f32_16x16x32_bf16(a, b[kc], acc, 0, 0, 0);
        }
        int och = mt * 16 + quad * 4;
        ushort4 au = *(const ushort4*)(agg2b + (size_t)nc * 64 + och);
        float4 bv = *(const float4*)(b2 + och);
        hs[wv * 16 + col][och + 0] = fmaxf(acc[0] + __uint_as_float((unsigned)au.x << 16) + bv.x, 0.f);
        hs[wv * 16 + col][och + 1] = fmaxf(acc[1] + __uint_as_float((unsigned)au.y << 16) + bv.y, 0.f);
        hs[wv * 16 + col][och + 2] = fmaxf(acc[2] + __uint_as_float((unsigned)au.z << 16) + bv.z, 0.f);
        hs[wv * 16 + col][och + 3] = fmaxf(acc[3] + __uint_as_float((unsigned)au.w << 16) + bv.w, 0.f);
    }
    __syncthreads();

    for (int o = tid; o < 64 * N_CLS; o += 256) {
        int n = o / N_CLS, cls = o % N_CLS;
        if (node0 + n >= N_NODES) continue;
        float s = bcs[cls];
#pragma unroll
        for (int k = 0; k < 64; ++k) s += hs[n][k] * wcs[k * N_CLS + cls];
        out[(size_t)(node0 + n) * N_CLS + cls] = s;
    }
}

// ---------------------------------------------------------------------------

extern "C" void kernel_launch(void* const* d_in, const int* in_sizes, int n_in,
                              void* d_out, int out_size, void* d_ws, size_t ws_size,
                              hipStream_t stream)
{
    const float* x        = (const float*)d_in[0];
    const int*   ei       = (const int*)  d_in[1];
    const float* w_self1  = (const float*)d_in[2];
    const float* w_neigh1 = (const float*)d_in[3];
    const float* b1       = (const float*)d_in[4];
    const float* w_self2  = (const float*)d_in[5];
    const float* w_neigh2 = (const float*)d_in[6];
    const float* b2       = (const float*)d_in[7];
    const float* wc       = (const float*)d_in[8];
    const float* bc       = (const float*)d_in[9];
    float* out = (float*)d_out;

    const size_t N = N_NODES;
    int*      bcnt    = (int*)d_ws;                       // BUCKETS*XSL
    int*      bbase   = bcnt + BUCKETS * XSL;             // 200
    int*      row_ptr = bbase + 200;                      // N+8
    unsigned* bins    = (unsigned*)(row_ptr + N + 8);     // BUCKETS*XSL*WCAP
    int*      s_src   = (int*)(bins + BUCKETS * XSL * WCAP);  // E
    float*    dinv    = (float*)(s_src + N_EDGES);        // N
    unsigned short* xb    = (unsigned short*)(dinv + N);
    unsigned short* agg1b = xb + 64 * N;
    unsigned short* h1b   = agg1b + 64 * N;               // N x 128
    unsigned short* t2b   = h1b + 128 * N;                // N x 64
    unsigned short* agg2b = t2b + 64 * N;                 // N x 64
    unsigned short* wt1s  = agg2b + 64 * N;               // 128x64
    unsigned short* wt1n  = wt1s + 8192;
    unsigned short* wt2s  = wt1n + 8192;                  // 64x128
    unsigned short* wt2n  = wt2s + 8192;

    hipMemsetAsync(bcnt, 0, BUCKETS * XSL * sizeof(int), stream);

    const int EB2 = (N_EDGES + EPB - 1) / EPB;     // 391
    const int GB = (N_NODES * 8) / 256;            // 3125
    const int MB = (N_NODES + 63) / 64;            // 1563

    cvt_x_kernel<<<(N_NODES * 64 / 8 + 255) / 256, 256, 0, stream>>>(x, xb);
    prep_wt_kernel<<<64, 256, 0, stream>>>(w_self1, w_neigh1, w_self2, w_neigh2,
                                           wt1s, wt1n, wt2s, wt2n);

    binA_kernel<<<EB2, 256, 0, stream>>>(ei, bcnt, bins);
    bscan_kernel<<<1, 256, 0, stream>>>(bcnt, bbase, row_ptr);
    buildB_kernel<<<BUCKETS, 256, 0, stream>>>(bcnt, bins, bbase,
                                               row_ptr, s_src, dinv);

    gatherb_kernel<<<GB, 256, 0, stream>>>(row_ptr, s_src, xb, dinv, agg1b);
    dense1_mfma<<<MB, 256, 0, stream>>>(xb, agg1b, wt1s, wt1n, b1, h1b);
    t2_mfma<<<MB, 256, 0, stream>>>(h1b, wt2n, t2b);
    gatherb_kernel<<<GB, 256, 0, stream>>>(row_ptr, s_src, t2b, dinv, agg2b);
    dense2_cls_mfma<<<MB, 256, 0, stream>>>(h1b, wt2s, agg2b, b2, wc, bc, out);
}